// Round 5
// baseline (123.121 us; speedup 1.0000x reference)
//
#include <hip/hip_runtime.h>
#include <hip/hip_bf16.h>

typedef __attribute__((ext_vector_type(4))) int i32x4;

#define M_DIM 8192
#define K_DIM 1024
#define N_DIM 4096
#define OUT_ELEMS (M_DIM * (size_t)N_DIM)

static __device__ __forceinline__ void gload_lds16(const void* g, void* l) {
  __builtin_amdgcn_global_load_lds((__attribute__((address_space(1))) void*)g,
                                   (__attribute__((address_space(3))) void*)l,
                                   16, 0, 0);
}

// monotone float<->uint encoding for atomic min/max
static __device__ __forceinline__ unsigned enc(float f) {
  unsigned u = __float_as_uint(f);
  return (u >> 31) ? ~u : (u ^ 0x80000000u);
}
static __device__ __forceinline__ float dec(unsigned e) {
  return (e >> 31) ? __uint_as_float(e ^ 0x80000000u) : __uint_as_float(~e);
}

// pack 4 int-valued floats into one i32 as signed bytes (unsigned shifts: no UB)
static __device__ __forceinline__ int pack4(float a, float b, float c, float d) {
  unsigned v0 = (unsigned)(int)a & 255u, v1 = (unsigned)(int)b & 255u;
  unsigned v2 = (unsigned)(int)c & 255u, v3 = (unsigned)(int)d & 255u;
  return (int)(v0 | (v1 << 8) | (v2 << 16) | (v3 << 24));
}

// -------- Kernel A: per-channel weight quant (int8) + IntGELU per-channel constants ----
__global__ __launch_bounds__(256) void k_prep_w(
    const float* __restrict__ w, const float* __restrict__ bias,
    const float* __restrict__ prev_sf,
    int* __restrict__ wq, float* __restrict__ pb, float* __restrict__ pbg,
    float* __restrict__ pcg, float* __restrict__ psh, float* __restrict__ posf,
    unsigned* __restrict__ mm) {
  const int o = blockIdx.x;
  const int t = threadIdx.x;
  const float4 wv = *(const float4*)(w + (size_t)o * K_DIM + t * 4);
  float m = fmaxf(fmaxf(fabsf(wv.x), fabsf(wv.y)), fmaxf(fabsf(wv.z), fabsf(wv.w)));
  __shared__ float red[256];
  red[t] = m;
  __syncthreads();
  for (int s = 128; s > 0; s >>= 1) {
    if (t < s) red[t] = fmaxf(red[t], red[t + s]);
    __syncthreads();
  }
  const float fc = fmaxf(red[0], 1e-8f) / 127.f;  // fc_sf[o]
  wq[o * (K_DIM / 4) + t] = pack4(
      fminf(fmaxf(rintf(wv.x / fc), -127.f), 126.f),
      fminf(fmaxf(rintf(wv.y / fc), -127.f), 126.f),
      fminf(fmaxf(rintf(wv.z / fc), -127.f), 126.f),
      fminf(fmaxf(rintf(wv.w / fc), -127.f), 126.f));
  if (t == 0) {
    const float psf = prev_sf[0];
    const float bsf = fc * psf;  // bias_sf
    float bi = fminf(fmaxf(rintf(bias[o] / bsf), -2147483647.f), 2147483646.f);
    const float sfe = bsf / 1.4142f;
    const float bg = floorf(-1.769f / sfe);
    const float cF = (float)(1.0 / -0.2888);
    const float se2 = sfe * sfe;
    const float cg = floorf(cF / se2);
    const float sig = (se2 * -0.2888f) * 16384.f;   // sf_e^2 * a * 2^14
    const float sh = floorf(1.0f / sig);            // shift (negative)
    const float osf = (bsf * sig) * 0.5f;           // out_sf (negative)
    pb[o] = bi; pbg[o] = bg; pcg[o] = cg; psh[o] = sh; posf[o] = osf;
  }
  if (o == 0 && t == 0) {  // init global min/max (encoded 0.0f)
    mm[0] = 0x80000000u;
    mm[1] = 0x80000000u;
  }
}

// -------- Kernel B: activation -> exact-integer int8 --------
__global__ __launch_bounds__(256) void k_quant_x(
    const float* __restrict__ x, const float* __restrict__ prev_sf,
    int4* __restrict__ xq) {
  const size_t i = ((size_t)blockIdx.x * 256 + threadIdx.x) * 16;
  const float inv = 1.0f / prev_sf[0];
  const float4 v0 = *(const float4*)(x + i);
  const float4 v1 = *(const float4*)(x + i + 4);
  const float4 v2 = *(const float4*)(x + i + 8);
  const float4 v3 = *(const float4*)(x + i + 12);
  int4 q;
  q.x = pack4(rintf(v0.x * inv), rintf(v0.y * inv), rintf(v0.z * inv), rintf(v0.w * inv));
  q.y = pack4(rintf(v1.x * inv), rintf(v1.y * inv), rintf(v1.z * inv), rintf(v1.w * inv));
  q.z = pack4(rintf(v2.x * inv), rintf(v2.y * inv), rintf(v2.z * inv), rintf(v2.w * inv));
  q.w = pack4(rintf(v3.x * inv), rintf(v3.y * inv), rintf(v3.z * inv), rintf(v3.w * inv));
  xq[i / 16] = q;
}

// -------- Kernel C: int8 MFMA GEMM, counted-vmcnt ring-4 pipeline (m201 template) ------
// 256x256 tile, 8 waves (2Mx4N). K = 16 slots of 64 bytes. LDS: A ring-4 x 16KB +
// B ring-4 x 16KB = 128KB. Slot row = 64B (4 chunks of 16B), chunk swizzle
// c' = c ^ (row&3) ^ ((row>>2)&3), applied on the pre-swizzled GLOBAL source
// (LDS dest linear, rule #21) and on the ds_read address (same involution).
// Per phase: 12 ds_read_b128 -> stage slot s+3 (4 gload_lds/thread) -> vmcnt(8)
// (2 slots in flight, never 0 mid-loop) -> barrier -> 32 MFMA -> lgkmcnt(0) -> barrier.
__global__ __launch_bounds__(512, 2) void k_gemm(
    const char* __restrict__ A, const char* __restrict__ B,
    const float* __restrict__ pb, const float* __restrict__ pbg,
    const float* __restrict__ pcg, const float* __restrict__ psh,
    const float* __restrict__ posf,
    float* __restrict__ out, unsigned* __restrict__ mm) {
  __shared__ __align__(16) char smem[131072];
  __shared__ float smn[8], smx[8];
  const int t = threadIdx.x;
  const int wave = t >> 6, lane = t & 63;
  const int wm = wave >> 2, wn = wave & 3;          // 2x4 wave grid
  const int r16 = lane & 15, q4 = lane >> 4;
  // XCD-local 8x8 (M,N) sub-grid: per-XCD working set = 2MB A + 2MB B = 4MB = L2
  const int lin = blockIdx.x;
  const int xcd = lin & 7, j = lin >> 3;
  const int mblk = (xcd >> 1) * 8 + (j >> 3);       // [0,32)
  const int nblk = (xcd & 1) * 8 + (j & 7);         // [0,16)
  const int brow = mblk * 256, bcol = nblk * 256;
  // staging constants: one issue = 512 threads x 16B = 128 rows; src chunk pre-swizzled
  const int srow = lane >> 2;                        // row-in-16-row wave window
  const int scs = (lane & 3) ^ ((lane >> 2) & 3) ^ ((lane >> 4) & 3);  // src chunk
  // ds_read constants: chunk' = q4 ^ (row&3) ^ ((row>>2)&3); row = ...*16 + r16
  const int csw = (q4 ^ (r16 & 3) ^ ((r16 >> 2) & 3)) * 16;
  const int aoff0 = (wm * 128 + r16) * 64 + csw;
  const int boff0 = 65536 + (wn * 64 + r16) * 64 + csw;
  i32x4 acc[8][4] = {};

  auto stage = [&](int s) {
    const int ring = (s & 3) * 16384;
    const int kof = s * 64;
#pragma unroll
    for (int issue = 0; issue < 2; ++issue) {
      const int rl = issue * 128 + wave * 16 + srow;  // slot-local row (per-lane src)
      gload_lds16(A + (size_t)(brow + rl) * K_DIM + kof + scs * 16,
                  smem + ring + issue * 8192 + wave * 1024);          // uniform dest
      gload_lds16(B + (size_t)(bcol + rl) * K_DIM + kof + scs * 16,
                  smem + 65536 + ring + issue * 8192 + wave * 1024);  // uniform dest
    }
  };

#define PHASE(S, WAITASM, DO_STAGE)                                              \
  do {                                                                           \
    const int ring = ((S) & 3) * 16384;                                          \
    i32x4 af[8], bfr[4];                                                         \
    _Pragma("unroll") for (int mf = 0; mf < 8; ++mf)                             \
        af[mf] = *(const i32x4*)(smem + ring + aoff0 + mf * 1024);               \
    _Pragma("unroll") for (int nf = 0; nf < 4; ++nf)                             \
        bfr[nf] = *(const i32x4*)(smem + ring + boff0 + nf * 1024);              \
    if (DO_STAGE) stage((S) + 3);                                                \
    asm volatile(WAITASM ::: "memory");                                          \
    asm volatile("s_barrier" ::: "memory");                                      \
    __builtin_amdgcn_s_setprio(1);                                               \
    _Pragma("unroll") for (int mf = 0; mf < 8; ++mf)                             \
        _Pragma("unroll") for (int nf = 0; nf < 4; ++nf)                         \
            acc[mf][nf] = __builtin_amdgcn_mfma_i32_16x16x64_i8(                 \
                af[mf], bfr[nf], acc[mf][nf], 0, 0, 0);                          \
    __builtin_amdgcn_s_setprio(0);                                               \
    asm volatile("s_waitcnt lgkmcnt(0)" ::: "memory");                           \
    asm volatile("s_barrier" ::: "memory");                                      \
  } while (0)

  // prologue: stage slots 0..2 (12 loads/thread); slot 0 complete when <=8 remain
  stage(0); stage(1); stage(2);
  asm volatile("s_waitcnt vmcnt(8)" ::: "memory");
  asm volatile("s_barrier" ::: "memory");

  for (int s = 0; s < 13; ++s) PHASE(s, "s_waitcnt vmcnt(8)", true);
  PHASE(13, "s_waitcnt vmcnt(4)", false);
  PHASE(14, "s_waitcnt vmcnt(0)", false);
  PHASE(15, "s_waitcnt vmcnt(0)", false);
#undef PHASE

  // epilogue: bias add + IntGELU, write pre-requant f32 value, track min/max
  float mn = 0.f, mx = 0.f;
#pragma unroll
  for (int nf = 0; nf < 4; ++nf) {
    const int ch = bcol + wn * 64 + nf * 16 + r16;
    const float bi = pb[ch], bg = pbg[ch], cg = pcg[ch], sh = psh[ch], osf = posf[ch];
#pragma unroll
    for (int mf = 0; mf < 8; ++mf) {
      const int row0 = brow + wm * 128 + mf * 16 + q4 * 4;
#pragma unroll
      for (int r = 0; r < 4; ++r) {
        const float x0 = (float)acc[mf][nf][r] + bi;             // out_int (exact)
        const float sgn = (x0 > 0.f) ? 1.f : ((x0 < 0.f) ? -1.f : 0.f);
        const float ai = fminf(fabsf(x0), -bg);
        const float tt = ai + bg;
        const float y = floorf((sgn * (tt * tt + cg)) * 6.103515625e-05f);  // /2^14
        const float xval = (x0 * (y + sh)) * osf;
        mn = fminf(mn, xval);
        mx = fmaxf(mx, xval);
        out[(size_t)(row0 + r) * N_DIM + ch] = xval;
      }
    }
  }
  for (int off = 32; off > 0; off >>= 1) {
    mn = fminf(mn, __shfl_down(mn, off));
    mx = fmaxf(mx, __shfl_down(mx, off));
  }
  if (lane == 0) { smn[wave] = mn; smx[wave] = mx; }
  __syncthreads();
  if (t == 0) {
    mn = fminf(fminf(fminf(smn[0], smn[1]), fminf(smn[2], smn[3])),
               fminf(fminf(smn[4], smn[5]), fminf(smn[6], smn[7])));
    mx = fmaxf(fmaxf(fmaxf(smx[0], smx[1]), fmaxf(smx[2], smx[3])),
               fmaxf(fmaxf(smx[4], smx[5]), fmaxf(smx[6], smx[7])));
    atomicMin(&mm[0], enc(mn));
    atomicMax(&mm[1], enc(mx));
  }
}

// -------- Kernel D: global requant (QuantAct / FixedPointMul), in place on d_out ------
__global__ __launch_bounds__(256) void k_requant(
    float* __restrict__ out, const float* __restrict__ posf,
    const unsigned* __restrict__ mm) {
  const float xmn = dec(mm[0]);
  const float xmx = dec(mm[1]);
  const float asf = fmaxf(fmaxf(fabsf(xmn), fabsf(xmx)), 1e-8f) / 127.f;
  const size_t i = ((size_t)blockIdx.x * 256 + threadIdx.x) * 4;
  float4 xv = *(float4*)(out + i);
  const int o0 = (int)(i & (N_DIM - 1));
  const float4 sf4 = *(const float4*)(posf + o0);
  float xs[4] = {xv.x, xv.y, xv.z, xv.w};
  float ps[4] = {sf4.x, sf4.y, sf4.z, sf4.w};
  float rs[4];
#pragma unroll
  for (int r = 0; r < 4; ++r) {
    const float z = rintf(xs[r] / ps[r]);
    int e;
    const float mfr = frexpf(ps[r] / asf, &e);
    const float mi = floorf(mfr * 2147483648.f + 0.5f);
    float q = rintf((z * mi) * ldexpf(1.0f, e - 31));
    q = fminf(fmaxf(q, -128.f), 127.f);
    rs[r] = q * asf;
  }
  xv.x = rs[0]; xv.y = rs[1]; xv.z = rs[2]; xv.w = rs[3];
  *(float4*)(out + i) = xv;
  if (blockIdx.x == 0 && threadIdx.x == 0) out[OUT_ELEMS] = asf;  // trailing sf scalar
}

extern "C" void kernel_launch(void* const* d_in, const int* in_sizes, int n_in,
                              void* d_out, int out_size, void* d_ws, size_t ws_size,
                              hipStream_t stream) {
  const float* x = (const float*)d_in[0];
  const float* psf = (const float*)d_in[1];
  const float* w = (const float*)d_in[2];
  const float* bias = (const float*)d_in[3];
  float* out = (float*)d_out;
  char* ws = (char*)d_ws;

  int* wq = (int*)ws;                                     // 4 MiB (i8)
  char* xq = ws + 4194304;                                // 8 MiB (i8)
  float* pb = (float*)(ws + 12582912);                    // 5 x 16 KiB
  float* pbg = pb + N_DIM;
  float* pcg = pb + 2 * N_DIM;
  float* psh = pb + 3 * N_DIM;
  float* posf = pb + 4 * N_DIM;
  unsigned* mm = (unsigned*)(pb + 5 * N_DIM + 16);        // 2 x u32 min/max

  k_prep_w<<<dim3(N_DIM), dim3(256), 0, stream>>>(w, bias, psf, wq, pb, pbg, pcg, psh, posf, mm);
  k_quant_x<<<dim3((M_DIM * K_DIM) / (256 * 16)), dim3(256), 0, stream>>>(x, psf, (int4*)xq);
  k_gemm<<<dim3(512), dim3(512), 0, stream>>>(xq, (const char*)wq, pb, pbg, pcg, psh, posf, out, mm);
  k_requant<<<dim3((int)(OUT_ELEMS / (256 * 4))), dim3(256), 0, stream>>>(out, posf, mm);
}

// Round 6
// 123.057 us; speedup vs baseline: 1.0005x; 1.0005x over previous
//
#include <hip/hip_runtime.h>
#include <hip/hip_bf16.h>

typedef __attribute__((ext_vector_type(4))) int i32x4;
typedef __attribute__((ext_vector_type(4))) _Float16 f16x4;
typedef unsigned short u16;

#define M_DIM 8192
#define K_DIM 1024
#define N_DIM 4096
#define OUT_ELEMS (M_DIM * (size_t)N_DIM)

static __device__ __forceinline__ void gload_lds16(const void* g, void* l) {
  __builtin_amdgcn_global_load_lds((__attribute__((address_space(1))) void*)g,
                                   (__attribute__((address_space(3))) void*)l,
                                   16, 0, 0);
}

// monotone float<->uint encoding for atomic min/max
static __device__ __forceinline__ unsigned enc(float f) {
  unsigned u = __float_as_uint(f);
  return (u >> 31) ? ~u : (u ^ 0x80000000u);
}
static __device__ __forceinline__ float dec(unsigned e) {
  return (e >> 31) ? __uint_as_float(e ^ 0x80000000u) : __uint_as_float(~e);
}

// pack 4 int-valued floats into one i32 as signed bytes (unsigned shifts: no UB)
static __device__ __forceinline__ int pack4(float a, float b, float c, float d) {
  unsigned v0 = (unsigned)(int)a & 255u, v1 = (unsigned)(int)b & 255u;
  unsigned v2 = (unsigned)(int)c & 255u, v3 = (unsigned)(int)d & 255u;
  return (int)(v0 | (v1 << 8) | (v2 << 16) | (v3 << 24));
}

// -------- Kernel A: per-channel weight quant (int8) + IntGELU per-channel constants ----
__global__ __launch_bounds__(256) void k_prep_w(
    const float* __restrict__ w, const float* __restrict__ bias,
    const float* __restrict__ prev_sf,
    int* __restrict__ wq, float* __restrict__ pb, float* __restrict__ pbg,
    float* __restrict__ pcg, float* __restrict__ psh, float* __restrict__ posf,
    unsigned* __restrict__ mm) {
  const int o = blockIdx.x;
  const int t = threadIdx.x;
  const float4 wv = *(const float4*)(w + (size_t)o * K_DIM + t * 4);
  float m = fmaxf(fmaxf(fabsf(wv.x), fabsf(wv.y)), fmaxf(fabsf(wv.z), fabsf(wv.w)));
  __shared__ float red[256];
  red[t] = m;
  __syncthreads();
  for (int s = 128; s > 0; s >>= 1) {
    if (t < s) red[t] = fmaxf(red[t], red[t + s]);
    __syncthreads();
  }
  const float fc = fmaxf(red[0], 1e-8f) / 127.f;  // fc_sf[o]
  wq[o * (K_DIM / 4) + t] = pack4(
      fminf(fmaxf(rintf(wv.x / fc), -127.f), 126.f),
      fminf(fmaxf(rintf(wv.y / fc), -127.f), 126.f),
      fminf(fmaxf(rintf(wv.z / fc), -127.f), 126.f),
      fminf(fmaxf(rintf(wv.w / fc), -127.f), 126.f));
  if (t == 0) {
    const float psf = prev_sf[0];
    const float bsf = fc * psf;  // bias_sf
    float bi = fminf(fmaxf(rintf(bias[o] / bsf), -2147483647.f), 2147483646.f);
    const float sfe = bsf / 1.4142f;
    const float bg = floorf(-1.769f / sfe);
    const float cF = (float)(1.0 / -0.2888);
    const float se2 = sfe * sfe;
    const float cg = floorf(cF / se2);
    const float sig = (se2 * -0.2888f) * 16384.f;   // sf_e^2 * a * 2^14
    const float sh = floorf(1.0f / sig);            // shift (negative)
    const float osf = (bsf * sig) * 0.5f;           // out_sf (negative)
    pb[o] = bi; pbg[o] = bg; pcg[o] = cg; psh[o] = sh; posf[o] = osf;
  }
  if (o == 0 && t == 0) {  // init global min/max (encoded 0.0f)
    mm[0] = 0x80000000u;
    mm[1] = 0x80000000u;
  }
}

// -------- Kernel B: activation -> exact-integer int8 --------
__global__ __launch_bounds__(256) void k_quant_x(
    const float* __restrict__ x, const float* __restrict__ prev_sf,
    int4* __restrict__ xq) {
  const size_t i = ((size_t)blockIdx.x * 256 + threadIdx.x) * 16;
  const float inv = 1.0f / prev_sf[0];
  const float4 v0 = *(const float4*)(x + i);
  const float4 v1 = *(const float4*)(x + i + 4);
  const float4 v2 = *(const float4*)(x + i + 8);
  const float4 v3 = *(const float4*)(x + i + 12);
  int4 q;
  q.x = pack4(rintf(v0.x * inv), rintf(v0.y * inv), rintf(v0.z * inv), rintf(v0.w * inv));
  q.y = pack4(rintf(v1.x * inv), rintf(v1.y * inv), rintf(v1.z * inv), rintf(v1.w * inv));
  q.z = pack4(rintf(v2.x * inv), rintf(v2.y * inv), rintf(v2.z * inv), rintf(v2.w * inv));
  q.w = pack4(rintf(v3.x * inv), rintf(v3.y * inv), rintf(v3.z * inv), rintf(v3.w * inv));
  xq[i / 16] = q;
}

// -------- Kernel C: int8 MFMA GEMM + fused bias/IntGELU/minmax, fp16 interleaved out ---
// 256x256 tile, 8 waves (2Mx4N), K = 8 slots of 128 bytes. LDS ring-2 = 128KB; each
// slot = 2 sub-slots (k-lo/k-hi) of [256 rows][64B] with R2's MEASURED-ZERO-CONFLICT
// swizzle chunk' = q4 ^ ((r16>>1)&3), applied via pre-swizzled global source (LDS dest
// linear, rule #21). MFMA operands SWAPPED (mfma(B,A)) so each lane holds 4 consecutive
// output channels per fragment -> 8B fp16x4 stores. fp16 xval of element e stored at
// u16 index (e>>6)*128 + (e&63) inside d_out (first 128B of each 64-elem group's 256B
// f32 region; requant reads its own group then overwrites).
__global__ __launch_bounds__(512, 2) void k_gemm(
    const char* __restrict__ A, const char* __restrict__ B,
    const float* __restrict__ pb, const float* __restrict__ pbg,
    const float* __restrict__ pcg, const float* __restrict__ psh,
    const float* __restrict__ posf,
    float* __restrict__ out, unsigned* __restrict__ mm) {
  __shared__ __align__(16) char smem[131072];
  __shared__ float smn[8], smx[8];
  const int t = threadIdx.x;
  const int wave = t >> 6, lane = t & 63;
  const int wm = wave >> 2, wn = wave & 3;          // 2x4 wave grid
  const int r16 = lane & 15, q4 = lane >> 4;
  // XCD-local 8x8 (M,N) sub-grid: per-XCD working set = 2MB A + 2MB B = 4MB = L2
  const int lin = blockIdx.x;
  const int xcd = lin & 7, j = lin >> 3;
  const int mblk = (xcd >> 1) * 8 + (j >> 3);       // [0,32)
  const int nblk = (xcd & 1) * 8 + (j & 7);         // [0,16)
  const int brow = mblk * 256, bcol = nblk * 256;
  // ds_read constants (R2-proven pattern: 64B rows, chunk' = q4 ^ ((r16>>1)&3))
  const int csw = (q4 ^ ((r16 >> 1) & 3)) * 16;
  const int aoff = (wm * 128 + r16) * 64 + csw;
  const int boff = 32768 + (wn * 64 + r16) * 64 + csw;
  i32x4 acc[8][4] = {};

  auto stage = [&](int s) {
    const int ring = (s & 1) << 16;
    const int kof = s * 128;
    const int row2 = t >> 2;                                  // 0..127
    const int scs16 = ((t & 3) ^ ((t >> 3) & 3)) * 16;        // pre-swizzled src chunk
    const char* Ab  = A + (size_t)(brow + row2) * K_DIM + kof + scs16;
    const char* Ab2 = A + (size_t)(brow + 128 + row2) * K_DIM + kof + scs16;
    const char* Bb  = B + (size_t)(bcol + row2) * K_DIM + kof + scs16;
    const char* Bb2 = B + (size_t)(bcol + 128 + row2) * K_DIM + kof + scs16;
    char* d = smem + ring + t * 16;
    gload_lds16(Ab,       d);                 // A k-lo, rows 0-127
    gload_lds16(Ab + 64,  d + 16384);         // A k-hi, rows 0-127
    gload_lds16(Ab2,      d + 8192);          // A k-lo, rows 128-255
    gload_lds16(Ab2 + 64, d + 16384 + 8192);  // A k-hi, rows 128-255
    gload_lds16(Bb,       d + 32768);         // B k-lo
    gload_lds16(Bb + 64,  d + 49152);         // B k-hi
    gload_lds16(Bb2,      d + 32768 + 8192);
    gload_lds16(Bb2 + 64, d + 49152 + 8192);
  };

  stage(0);
  asm volatile("s_waitcnt vmcnt(0)" ::: "memory");
  __builtin_amdgcn_s_barrier();

  for (int s = 0; s < 8; ++s) {
    if (s < 7) stage(s + 1);
    const int ring = (s & 1) << 16;
#pragma unroll
    for (int kk = 0; kk < 2; ++kk) {
      const int kb = ring + kk * 16384;
      i32x4 af[8], bfr[4];
#pragma unroll
      for (int nf = 0; nf < 4; ++nf)
        bfr[nf] = *(const i32x4*)(smem + kb + boff + nf * 1024);
#pragma unroll
      for (int mf = 0; mf < 8; ++mf)
        af[mf] = *(const i32x4*)(smem + kb + aoff + mf * 1024);
      __builtin_amdgcn_s_setprio(1);
#pragma unroll
      for (int mf = 0; mf < 8; ++mf)
#pragma unroll
        for (int nf = 0; nf < 4; ++nf)   // SWAPPED operands: D[row<-B(ch)][col<-A(row)]
          acc[mf][nf] = __builtin_amdgcn_mfma_i32_16x16x64_i8(bfr[nf], af[mf], acc[mf][nf], 0, 0, 0);
      __builtin_amdgcn_s_setprio(0);
    }
    asm volatile("s_waitcnt vmcnt(0) lgkmcnt(0)" ::: "memory");
    __builtin_amdgcn_s_barrier();
  }

  // epilogue: lane holds ch = bcol+wn*64+nf*16+q4*4+j (j=reg), row = brow+wm*128+mf*16+r16
  u16* zh = (u16*)out;
  float mn = 0.f, mx = 0.f;
#pragma unroll
  for (int nf = 0; nf < 4; ++nf) {
    const int ch0 = bcol + wn * 64 + nf * 16 + q4 * 4;
    const float4 bi4 = *(const float4*)(pb + ch0);
    const float4 bg4 = *(const float4*)(pbg + ch0);
    const float4 cg4 = *(const float4*)(pcg + ch0);
    const float4 sh4 = *(const float4*)(psh + ch0);
    const float4 os4 = *(const float4*)(posf + ch0);
    const float bis[4] = {bi4.x, bi4.y, bi4.z, bi4.w};
    const float bgs[4] = {bg4.x, bg4.y, bg4.z, bg4.w};
    const float cgs[4] = {cg4.x, cg4.y, cg4.z, cg4.w};
    const float shs[4] = {sh4.x, sh4.y, sh4.z, sh4.w};
    const float oss[4] = {os4.x, os4.y, os4.z, os4.w};
    const size_t zb = ((size_t)(ch0 >> 6)) * 128 + (ch0 & 63);  // group-interleave base
#pragma unroll
    for (int mf = 0; mf < 8; ++mf) {
      const int row = brow + wm * 128 + mf * 16 + r16;
      f16x4 hv;
#pragma unroll
      for (int jj = 0; jj < 4; ++jj) {
        const float x0 = (float)acc[mf][nf][jj] + bis[jj];       // out_int (exact)
        const float sgn = (x0 > 0.f) ? 1.f : ((x0 < 0.f) ? -1.f : 0.f);
        const float ai = fminf(fabsf(x0), -bgs[jj]);
        const float tt = ai + bgs[jj];
        const float y = floorf((sgn * (tt * tt + cgs[jj])) * 6.103515625e-05f);  // /2^14
        const float xval = (x0 * (y + shs[jj])) * oss[jj];
        mn = fminf(mn, xval);
        mx = fmaxf(mx, xval);
        hv[jj] = (_Float16)xval;
      }
      *(f16x4*)(zh + (size_t)row * 8192 + zb) = hv;
    }
  }
  for (int off = 32; off > 0; off >>= 1) {
    mn = fminf(mn, __shfl_down(mn, off));
    mx = fmaxf(mx, __shfl_down(mx, off));
  }
  if (lane == 0) { smn[wave] = mn; smx[wave] = mx; }
  __syncthreads();
  if (t == 0) {
    mn = fminf(fminf(fminf(smn[0], smn[1]), fminf(smn[2], smn[3])),
               fminf(fminf(smn[4], smn[5]), fminf(smn[6], smn[7])));
    mx = fmaxf(fmaxf(fmaxf(smx[0], smx[1]), fmaxf(smx[2], smx[3])),
               fmaxf(fmaxf(smx[4], smx[5]), fmaxf(smx[6], smx[7])));
    atomicMin(&mm[0], enc(mn));
    atomicMax(&mm[1], enc(mx));
  }
}

// -------- Kernel D: requant; each wave reads its own groups' fp16 then overwrites ----
__global__ __launch_bounds__(256) void k_requant(
    float* out, const float* __restrict__ posf, const unsigned* __restrict__ mm) {
  const float xmn = dec(mm[0]);
  const float xmx = dec(mm[1]);
  const float asf = fmaxf(fmaxf(fabsf(xmn), fabsf(xmx)), 1e-8f) / 127.f;
  const unsigned tid = blockIdx.x * 256 + threadIdx.x;
  const unsigned W = tid >> 6, l = tid & 63;
  const size_t e0 = (size_t)W * 256 + 4u * l;                       // 4 output elems
  const size_t uidx = (size_t)W * 512 + (l >> 4) * 128 + (l & 15) * 4;  // their fp16
  const f16x4 hv = *(const f16x4*)((const u16*)out + uidx);
  const int o0 = (int)(e0 & (N_DIM - 1));
  const float4 sf4 = *(const float4*)(posf + o0);
  const float ps[4] = {sf4.x, sf4.y, sf4.z, sf4.w};
  float rs[4];
#pragma unroll
  for (int r = 0; r < 4; ++r) {
    const float z = rintf((float)hv[r] / ps[r]);
    int e;
    const float mfr = frexpf(ps[r] / asf, &e);
    const float mi = floorf(mfr * 2147483648.f + 0.5f);
    float q = rintf((z * mi) * ldexpf(1.0f, e - 31));
    q = fminf(fmaxf(q, -128.f), 127.f);
    rs[r] = q * asf;
  }
  float4 xv;
  xv.x = rs[0]; xv.y = rs[1]; xv.z = rs[2]; xv.w = rs[3];
  *(float4*)(out + e0) = xv;
  if (tid == 0) out[OUT_ELEMS] = asf;  // trailing sf scalar
}

extern "C" void kernel_launch(void* const* d_in, const int* in_sizes, int n_in,
                              void* d_out, int out_size, void* d_ws, size_t ws_size,
                              hipStream_t stream) {
  const float* x = (const float*)d_in[0];
  const float* psf = (const float*)d_in[1];
  const float* w = (const float*)d_in[2];
  const float* bias = (const float*)d_in[3];
  float* out = (float*)d_out;
  char* ws = (char*)d_ws;

  int* wq = (int*)ws;                                     // 4 MiB (i8)
  char* xq = ws + 4194304;                                // 8 MiB (i8)
  float* pb = (float*)(ws + 12582912);                    // 5 x 16 KiB
  float* pbg = pb + N_DIM;
  float* pcg = pb + 2 * N_DIM;
  float* psh = pb + 3 * N_DIM;
  float* posf = pb + 4 * N_DIM;
  unsigned* mm = (unsigned*)(pb + 5 * N_DIM + 16);        // 2 x u32 min/max

  k_prep_w<<<dim3(N_DIM), dim3(256), 0, stream>>>(w, bias, psf, wq, pb, pbg, pcg, psh, posf, mm);
  k_quant_x<<<dim3((M_DIM * K_DIM) / (256 * 16)), dim3(256), 0, stream>>>(x, psf, (int4*)xq);
  k_gemm<<<dim3(512), dim3(512), 0, stream>>>(xq, (const char*)wq, pb, pbg, pcg, psh, posf, out, mm);
  k_requant<<<dim3((int)(OUT_ELEMS / (256 * 4))), dim3(256), 0, stream>>>(out, posf, mm);
}

// Round 7
// 120.055 us; speedup vs baseline: 1.0255x; 1.0250x over previous
//
#include <hip/hip_runtime.h>
#include <hip/hip_bf16.h>

typedef __attribute__((ext_vector_type(4))) int i32x4;

#define M_DIM 8192
#define K_DIM 1024
#define N_DIM 4096
#define OUT_ELEMS (M_DIM * (size_t)N_DIM)

static __device__ __forceinline__ void gload_lds16(const void* g, void* l) {
  __builtin_amdgcn_global_load_lds((__attribute__((address_space(1))) void*)g,
                                   (__attribute__((address_space(3))) void*)l,
                                   16, 0, 0);
}

// monotone float<->uint encoding for atomic min/max
static __device__ __forceinline__ unsigned enc(float f) {
  unsigned u = __float_as_uint(f);
  return (u >> 31) ? ~u : (u ^ 0x80000000u);
}
static __device__ __forceinline__ float dec(unsigned e) {
  return (e >> 31) ? __uint_as_float(e ^ 0x80000000u) : __uint_as_float(~e);
}

// pack 4 int-valued floats into one i32 as signed bytes (unsigned shifts: no UB)
static __device__ __forceinline__ int pack4(float a, float b, float c, float d) {
  unsigned v0 = (unsigned)(int)a & 255u, v1 = (unsigned)(int)b & 255u;
  unsigned v2 = (unsigned)(int)c & 255u, v3 = (unsigned)(int)d & 255u;
  return (int)(v0 | (v1 << 8) | (v2 << 16) | (v3 << 24));
}

// -------- Kernel A: per-channel weight quant (int8) + IntGELU per-channel constants ----
__global__ __launch_bounds__(256) void k_prep_w(
    const float* __restrict__ w, const float* __restrict__ bias,
    const float* __restrict__ prev_sf,
    int* __restrict__ wq, float* __restrict__ pb, float* __restrict__ pbg,
    float* __restrict__ pcg, float* __restrict__ psh, float* __restrict__ posf,
    unsigned* __restrict__ mm) {
  const int o = blockIdx.x;
  const int t = threadIdx.x;
  const float4 wv = *(const float4*)(w + (size_t)o * K_DIM + t * 4);
  float m = fmaxf(fmaxf(fabsf(wv.x), fabsf(wv.y)), fmaxf(fabsf(wv.z), fabsf(wv.w)));
  __shared__ float red[256];
  red[t] = m;
  __syncthreads();
  for (int s = 128; s > 0; s >>= 1) {
    if (t < s) red[t] = fmaxf(red[t], red[t + s]);
    __syncthreads();
  }
  const float fc = fmaxf(red[0], 1e-8f) / 127.f;  // fc_sf[o]
  wq[o * (K_DIM / 4) + t] = pack4(
      fminf(fmaxf(rintf(wv.x / fc), -127.f), 126.f),
      fminf(fmaxf(rintf(wv.y / fc), -127.f), 126.f),
      fminf(fmaxf(rintf(wv.z / fc), -127.f), 126.f),
      fminf(fmaxf(rintf(wv.w / fc), -127.f), 126.f));
  if (t == 0) {
    const float psf = prev_sf[0];
    const float bsf = fc * psf;  // bias_sf
    float bi = fminf(fmaxf(rintf(bias[o] / bsf), -2147483647.f), 2147483646.f);
    const float sfe = bsf / 1.4142f;
    const float bg = floorf(-1.769f / sfe);
    const float cF = (float)(1.0 / -0.2888);
    const float se2 = sfe * sfe;
    const float cg = floorf(cF / se2);
    const float sig = (se2 * -0.2888f) * 16384.f;   // sf_e^2 * a * 2^14
    const float sh = floorf(1.0f / sig);            // shift (negative)
    const float osf = (bsf * sig) * 0.5f;           // out_sf (negative)
    pb[o] = bi; pbg[o] = bg; pcg[o] = cg; psh[o] = sh; posf[o] = osf;
  }
  if (o == 0 && t == 0) {  // init global min/max (encoded 0.0f)
    mm[0] = 0x80000000u;
    mm[1] = 0x80000000u;
  }
}

// -------- Kernel B: activation -> exact-integer int8 --------
__global__ __launch_bounds__(256) void k_quant_x(
    const float* __restrict__ x, const float* __restrict__ prev_sf,
    int4* __restrict__ xq) {
  const size_t i = ((size_t)blockIdx.x * 256 + threadIdx.x) * 16;
  const float inv = 1.0f / prev_sf[0];
  const float4 v0 = *(const float4*)(x + i);
  const float4 v1 = *(const float4*)(x + i + 4);
  const float4 v2 = *(const float4*)(x + i + 8);
  const float4 v3 = *(const float4*)(x + i + 12);
  int4 q;
  q.x = pack4(rintf(v0.x * inv), rintf(v0.y * inv), rintf(v0.z * inv), rintf(v0.w * inv));
  q.y = pack4(rintf(v1.x * inv), rintf(v1.y * inv), rintf(v1.z * inv), rintf(v1.w * inv));
  q.z = pack4(rintf(v2.x * inv), rintf(v2.y * inv), rintf(v2.z * inv), rintf(v2.w * inv));
  q.w = pack4(rintf(v3.x * inv), rintf(v3.y * inv), rintf(v3.z * inv), rintf(v3.w * inv));
  xq[i / 16] = q;
}

// -------- Kernel C: int8 MFMA GEMM (exact i32) + fused bias/IntGELU/minmax, f32 out ----
// 256x256 tile, 8 waves (2Mx4N), K = 8 slots of 128 bytes. LDS ring-2:
// A 2x32KB + B 2x32KB = 128KB. Slot row = 128B (8 chunks of 16B), chunk swizzled
// c' = c ^ (row&7) via pre-swizzled global source (LDS dest linear, rule #21);
// analytically 2 lanes/bank on read and write (free per m136).
// R7 schedule (counted vmcnt, 2-slot-deep pipeline; replaces R4's per-phase drain):
//   stage(0); stage(1); vmcnt(8); bar
//   for s: {ds_read+MFMA slot s}; lgkmcnt(0); bar;     <- WAR: ring s&1 reads done
//          if s<6 stage(s+2); vmcnt(8)|vmcnt(0); bar   <- slot s+1 complete
// Slot s+1's loads land during slot s's MFMA window (~2600 cyc >> HBM latency).
__global__ __launch_bounds__(512, 2) void k_gemm(
    const char* __restrict__ A, const char* __restrict__ B,
    const float* __restrict__ pb, const float* __restrict__ pbg,
    const float* __restrict__ pcg, const float* __restrict__ psh,
    const float* __restrict__ posf,
    float* __restrict__ out, unsigned* __restrict__ mm) {
  __shared__ __align__(16) char smem[131072];
  __shared__ float smn[8], smx[8];
  const int t = threadIdx.x;
  const int wave = t >> 6, lane = t & 63;
  const int wm = wave >> 2, wn = wave & 3;          // 2x4 wave grid
  const int r16 = lane & 15, q4 = lane >> 4;
  // XCD-local 8x8 (M,N) sub-grid: per-XCD working set = 2MB A + 2MB B = 4MB = L2
  const int lin = blockIdx.x;
  const int xcd = lin & 7, j = lin >> 3;
  const int mblk = (xcd >> 1) * 8 + (j >> 3);       // [0,32)
  const int nblk = (xcd & 1) * 8 + (j & 7);         // [0,16)
  const int brow = mblk * 256, bcol = nblk * 256;
  // staging constants: window = 8 rows x 128B; source chunk pre-swizzled
  const int sr = lane >> 3;                          // row in window
  const int sc = (lane & 7) ^ (sr & 7);              // swizzled 16B chunk
  // ds_read constants
  const int cs0 = (q4 ^ (r16 & 7)) * 16;             // kk=0 chunk byte
  const int cs1 = ((4 + q4) ^ (r16 & 7)) * 16;       // kk=1 chunk byte
  const int aB = (wm * 128 + r16) * 128;
  const int bB = 65536 + (wn * 64 + r16) * 128;
  i32x4 acc[8][4] = {};

  auto stage = [&](int s) {
    const int ring = (s & 1) << 15;
    const int kof = s * 128;
#pragma unroll
    for (int jw = 0; jw < 4; ++jw) {
      const int rowg = wave * 32 + jw * 8;
      gload_lds16(A + (size_t)(brow + rowg + sr) * K_DIM + kof + sc * 16,
                  smem + ring + rowg * 128);
      gload_lds16(B + (size_t)(bcol + rowg + sr) * K_DIM + kof + sc * 16,
                  smem + 65536 + ring + rowg * 128);
    }
  };

  // prologue: 2 slots in flight; wait for slot 0 (8 newest = slot 1 stay in flight)
  stage(0);
  stage(1);
  asm volatile("s_waitcnt vmcnt(8)" ::: "memory");
  asm volatile("s_barrier" ::: "memory");

  for (int s = 0; s < 8; ++s) {
    const int ring = (s & 1) << 15;
#pragma unroll
    for (int kk = 0; kk < 2; ++kk) {
      const int cs = kk ? cs1 : cs0;
      i32x4 af[8], bfr[4];
#pragma unroll
      for (int nf = 0; nf < 4; ++nf)
        bfr[nf] = *(const i32x4*)(smem + ring + bB + nf * 2048 + cs);
#pragma unroll
      for (int mf = 0; mf < 8; ++mf)
        af[mf] = *(const i32x4*)(smem + ring + aB + mf * 2048 + cs);
      __builtin_amdgcn_s_setprio(1);
#pragma unroll
      for (int mf = 0; mf < 8; ++mf)
#pragma unroll
        for (int nf = 0; nf < 4; ++nf)
          acc[mf][nf] = __builtin_amdgcn_mfma_i32_16x16x64_i8(af[mf], bfr[nf], acc[mf][nf], 0, 0, 0);
      __builtin_amdgcn_s_setprio(0);
    }
    // WAR guard: all waves' ds_reads of ring s&1 complete before restaging into it
    asm volatile("s_waitcnt lgkmcnt(0)" ::: "memory");
    asm volatile("s_barrier" ::: "memory");
    if (s < 6) {
      stage(s + 2);  // into ring s&1 (just-freed)
      asm volatile("s_waitcnt vmcnt(8)" ::: "memory");   // slot s+1 complete
    } else {
      asm volatile("s_waitcnt vmcnt(0)" ::: "memory");   // tail drain
    }
    asm volatile("s_barrier" ::: "memory");
  }

  // epilogue: bias add + IntGELU, write pre-requant f32 value, track min/max
  float mn = 0.f, mx = 0.f;
#pragma unroll
  for (int nf = 0; nf < 4; ++nf) {
    const int ch = bcol + wn * 64 + nf * 16 + r16;
    const float bi = pb[ch], bg = pbg[ch], cg = pcg[ch], sh = psh[ch], osf = posf[ch];
#pragma unroll
    for (int mf = 0; mf < 8; ++mf) {
      const int row0 = brow + wm * 128 + mf * 16 + q4 * 4;
#pragma unroll
      for (int r = 0; r < 4; ++r) {
        const float x0 = (float)acc[mf][nf][r] + bi;             // out_int (exact, <2^24)
        const float sgn = (x0 > 0.f) ? 1.f : ((x0 < 0.f) ? -1.f : 0.f);
        const float ai = fminf(fabsf(x0), -bg);
        const float tt = ai + bg;
        const float y = floorf((sgn * (tt * tt + cg)) * 6.103515625e-05f);  // /2^14
        const float xval = (x0 * (y + sh)) * osf;
        mn = fminf(mn, xval);
        mx = fmaxf(mx, xval);
        out[(size_t)(row0 + r) * N_DIM + ch] = xval;
      }
    }
  }
  for (int off = 32; off > 0; off >>= 1) {
    mn = fminf(mn, __shfl_down(mn, off));
    mx = fmaxf(mx, __shfl_down(mx, off));
  }
  if (lane == 0) { smn[wave] = mn; smx[wave] = mx; }
  __syncthreads();
  if (t == 0) {
    mn = fminf(fminf(fminf(smn[0], smn[1]), fminf(smn[2], smn[3])),
               fminf(fminf(smn[4], smn[5]), fminf(smn[6], smn[7])));
    mx = fmaxf(fmaxf(fmaxf(smx[0], smx[1]), fmaxf(smx[2], smx[3])),
               fmaxf(fmaxf(smx[4], smx[5]), fmaxf(smx[6], smx[7])));
    atomicMin(&mm[0], enc(mn));
    atomicMax(&mm[1], enc(mx));
  }
}

// -------- Kernel D: global requant (QuantAct / FixedPointMul), in place on d_out ------
__global__ __launch_bounds__(256) void k_requant(
    float* __restrict__ out, const float* __restrict__ posf,
    const unsigned* __restrict__ mm) {
  const float xmn = dec(mm[0]);
  const float xmx = dec(mm[1]);
  const float asf = fmaxf(fmaxf(fabsf(xmn), fabsf(xmx)), 1e-8f) / 127.f;
  const size_t i = ((size_t)blockIdx.x * 256 + threadIdx.x) * 4;
  float4 xv = *(float4*)(out + i);
  const int o0 = (int)(i & (N_DIM - 1));
  const float4 sf4 = *(const float4*)(posf + o0);
  float xs[4] = {xv.x, xv.y, xv.z, xv.w};
  float ps[4] = {sf4.x, sf4.y, sf4.z, sf4.w};
  float rs[4];
#pragma unroll
  for (int r = 0; r < 4; ++r) {
    const float z = rintf(xs[r] / ps[r]);
    int e;
    const float mfr = frexpf(ps[r] / asf, &e);
    const float mi = floorf(mfr * 2147483648.f + 0.5f);
    float q = rintf((z * mi) * ldexpf(1.0f, e - 31));
    q = fminf(fmaxf(q, -128.f), 127.f);
    rs[r] = q * asf;
  }
  xv.x = rs[0]; xv.y = rs[1]; xv.z = rs[2]; xv.w = rs[3];
  *(float4*)(out + i) = xv;
  if (blockIdx.x == 0 && threadIdx.x == 0) out[OUT_ELEMS] = asf;  // trailing sf scalar
}

extern "C" void kernel_launch(void* const* d_in, const int* in_sizes, int n_in,
                              void* d_out, int out_size, void* d_ws, size_t ws_size,
                              hipStream_t stream) {
  const float* x = (const float*)d_in[0];
  const float* psf = (const float*)d_in[1];
  const float* w = (const float*)d_in[2];
  const float* bias = (const float*)d_in[3];
  float* out = (float*)d_out;
  char* ws = (char*)d_ws;

  int* wq = (int*)ws;                                     // 4 MiB (i8)
  char* xq = ws + 4194304;                                // 8 MiB (i8)
  float* pb = (float*)(ws + 12582912);                    // 5 x 16 KiB
  float* pbg = pb + N_DIM;
  float* pcg = pb + 2 * N_DIM;
  float* psh = pb + 3 * N_DIM;
  float* posf = pb + 4 * N_DIM;
  unsigned* mm = (unsigned*)(pb + 5 * N_DIM + 16);        // 2 x u32 min/max

  k_prep_w<<<dim3(N_DIM), dim3(256), 0, stream>>>(w, bias, psf, wq, pb, pbg, pcg, psh, posf, mm);
  k_quant_x<<<dim3((M_DIM * K_DIM) / (256 * 16)), dim3(256), 0, stream>>>(x, psf, (int4*)xq);
  k_gemm<<<dim3(512), dim3(512), 0, stream>>>(xq, (const char*)wq, pb, pbg, pcg, psh, posf, out, mm);
  k_requant<<<dim3((int)(OUT_ELEMS / (256 * 4))), dim3(256), 0, stream>>>(out, posf, mm);
}